// Round 1
// baseline (565.818 us; speedup 1.0000x reference)
//
#include <hip/hip_runtime.h>
#include <math.h>

#define BB 1024
#define HH 1024
#define NN 32

typedef float f4 __attribute__((ext_vector_type(4)));

// ---------------------------------------------------------------------------
// Kernel 1: complex diag state update + C-readout + skip + exact GELU.
// 8 threads per (b,h) pair, each handling 4 consecutive n (float4 loads).
// Writes ns_re/ns_im to d_out regions, y=gelu(...) to workspace.
// ---------------------------------------------------------------------------
__global__ __launch_bounds__(256) void s4_update_kernel(
    const float* __restrict__ u,
    const float* __restrict__ sre,  const float* __restrict__ sim,
    const float* __restrict__ dAre, const float* __restrict__ dAim,
    const float* __restrict__ dBre, const float* __restrict__ dBim,
    const float* __restrict__ Cre,  const float* __restrict__ Cim,
    const float* __restrict__ Dv,
    float* __restrict__ nsre, float* __restrict__ nsim,
    float* __restrict__ Y)
{
    const int tid  = threadIdx.x;
    const long gid = (long)blockIdx.x * 256 + tid;
    const int pair = (int)(gid >> 3);         // b*H + h
    const int sub  = tid & 7;                 // 0..7 within pair
    const int n0   = sub << 2;                // 0,4,...,28
    const int h    = pair & (HH - 1);
    const size_t sbase = (size_t)pair * NN + n0;
    const int    pbase = h * NN + n0;

    const f4 a_re = *(const f4*)(dAre + pbase);
    const f4 a_im = *(const f4*)(dAim + pbase);
    const f4 b_re = *(const f4*)(dBre + pbase);
    const f4 b_im = *(const f4*)(dBim + pbase);
    const f4 c_re = *(const f4*)(Cre  + pbase);
    const f4 c_im = *(const f4*)(Cim  + pbase);
    const f4 s_re = *(const f4*)(sre + sbase);
    const f4 s_im = *(const f4*)(sim + sbase);
    const float uv = u[pair];

    f4 nre = a_re * s_re - a_im * s_im + b_re * uv;
    f4 nim = a_re * s_im + a_im * s_re + b_im * uv;

    *(f4*)(nsre + sbase) = nre;
    *(f4*)(nsim + sbase) = nim;

    f4 p = c_re * nre - c_im * nim;
    float part = p[0] + p[1] + p[2] + p[3];
    // reduce across the 8 lanes of this pair (lanes are contiguous in wave)
    part += __shfl_xor(part, 1, 64);
    part += __shfl_xor(part, 2, 64);
    part += __shfl_xor(part, 4, 64);

    if (sub == 0) {
        float yv = 2.0f * part + uv * Dv[h];
        // exact GELU: x * 0.5 * (1 + erf(x/sqrt(2)))
        float g = 0.5f * yv * (1.0f + erff(yv * 0.70710678118654752f));
        Y[pair] = g;
    }
}

// ---------------------------------------------------------------------------
// Kernel 2: z = Y @ W^T + b  (fp32, vector ALU — no fp32 MFMA on CDNA4),
// fused GLU: out[:, j] = z1[:, j] * sigmoid(z2[:, j]).
// Tile: 64 rows x 64 out-cols (both W halves staged). BK=16.
// LDS rows padded to 68 floats => 16B-aligned rows, conflict-light.
// ---------------------------------------------------------------------------
__global__ __launch_bounds__(256) void s4_gemm_glu_kernel(
    const float* __restrict__ Y, const float* __restrict__ W,
    const float* __restrict__ bias, float* __restrict__ out)
{
    __shared__ float Ys [16][68];
    __shared__ float W1s[16][68];
    __shared__ float W2s[16][68];

    const int tid  = threadIdx.x;
    const int row0 = blockIdx.y * 64;   // Y/out row tile
    const int jc0  = blockIdx.x * 64;   // out col tile (half-index)

    // staging assignment: 64 rows x 4 float4-chunks of K
    const int lr = tid >> 2;            // 0..63
    const int lk = (tid & 3) << 2;      // 0,4,8,12

    const float* Yg  = Y + (size_t)(row0 + lr) * HH + lk;
    const float* W1g = W + (size_t)(jc0 + lr) * HH + lk;
    const float* W2g = W + (size_t)(jc0 + 1024 + lr) * HH + lk;

    // compute assignment: 16x16 thread grid, 4x4 outputs per half
    const int tc = tid & 15;
    const int tr = tid >> 4;

    float acc1[4][4] = {{0.f}};
    float acc2[4][4] = {{0.f}};

    for (int k0 = 0; k0 < HH; k0 += 16) {
        const f4 yv = *(const f4*)(Yg  + k0);
        const f4 w1 = *(const f4*)(W1g + k0);
        const f4 w2 = *(const f4*)(W2g + k0);

        __syncthreads();   // previous iteration's reads complete
        #pragma unroll
        for (int i = 0; i < 4; ++i) {
            Ys [lk + i][lr] = yv[i];
            W1s[lk + i][lr] = w1[i];
            W2s[lk + i][lr] = w2[i];
        }
        __syncthreads();

        #pragma unroll
        for (int kk = 0; kk < 16; ++kk) {
            const f4 ya  = *(const f4*)&Ys [kk][tr << 2];
            const f4 wa1 = *(const f4*)&W1s[kk][tc << 2];
            const f4 wa2 = *(const f4*)&W2s[kk][tc << 2];
            #pragma unroll
            for (int i = 0; i < 4; ++i) {
                #pragma unroll
                for (int j = 0; j < 4; ++j) {
                    acc1[i][j] = fmaf(ya[i], wa1[j], acc1[i][j]);
                    acc2[i][j] = fmaf(ya[i], wa2[j], acc2[i][j]);
                }
            }
        }
    }

    // epilogue: bias + GLU
    float b1[4], b2[4];
    #pragma unroll
    for (int j = 0; j < 4; ++j) {
        b1[j] = bias[jc0 + (tc << 2) + j];
        b2[j] = bias[jc0 + 1024 + (tc << 2) + j];
    }
    #pragma unroll
    for (int i = 0; i < 4; ++i) {
        f4 o;
        #pragma unroll
        for (int j = 0; j < 4; ++j) {
            float z1 = acc1[i][j] + b1[j];
            float z2 = acc2[i][j] + b2[j];
            o[j] = z1 * (1.0f / (1.0f + expf(-z2)));
        }
        *(f4*)(out + (size_t)(row0 + (tr << 2) + i) * HH + jc0 + (tc << 2)) = o;
    }
}

extern "C" void kernel_launch(void* const* d_in, const int* in_sizes, int n_in,
                              void* d_out, int out_size, void* d_ws, size_t ws_size,
                              hipStream_t stream) {
    const float* u    = (const float*)d_in[0];
    const float* sre  = (const float*)d_in[1];
    const float* sim  = (const float*)d_in[2];
    const float* dAre = (const float*)d_in[3];
    const float* dAim = (const float*)d_in[4];
    const float* dBre = (const float*)d_in[5];
    const float* dBim = (const float*)d_in[6];
    const float* Cre  = (const float*)d_in[7];
    const float* Cim  = (const float*)d_in[8];
    const float* Dv   = (const float*)d_in[9];
    const float* W    = (const float*)d_in[10];
    const float* bias = (const float*)d_in[11];

    float* out   = (float*)d_out;
    float* y_out = out;                                   // [B,H]
    float* nsre  = out + (size_t)BB * HH;                 // [B,H,N]
    float* nsim  = nsre + (size_t)BB * HH * NN;           // [B,H,N]
    float* Yws   = (float*)d_ws;                          // [B,H] fp32 scratch

    // K1: 8 threads per (b,h) pair
    const long total_threads = (long)BB * HH * 8;
    s4_update_kernel<<<dim3((unsigned)(total_threads / 256)), 256, 0, stream>>>(
        u, sre, sim, dAre, dAim, dBre, dBim, Cre, Cim, Dv, nsre, nsim, Yws);

    // K2: 16x16 tile grid (64 rows x 64 out-cols each)
    s4_gemm_glu_kernel<<<dim3(16, 16), 256, 0, stream>>>(Yws, W, bias, y_out);
}

// Round 7
// 538.591 us; speedup vs baseline: 1.0506x; 1.0506x over previous
//
#include <hip/hip_runtime.h>
#include <math.h>

#define BB 1024
#define HH 1024
#define NN 32

typedef float f4     __attribute__((ext_vector_type(4)));
typedef float f32x4  __attribute__((ext_vector_type(4)));
typedef short bf16x8 __attribute__((ext_vector_type(8)));
typedef short s4v    __attribute__((ext_vector_type(4)));

// float -> bf16 round-to-nearest-even, as raw short (avoids hip_bf16 API deps)
static __device__ __forceinline__ short f2bf(float x) {
    unsigned u = __builtin_bit_cast(unsigned, x);
    u += 0x7fff + ((u >> 16) & 1);
    return (short)(u >> 16);
}
static __device__ __forceinline__ float bf2f(short h) {
    unsigned u = ((unsigned)(unsigned short)h) << 16;
    return __builtin_bit_cast(float, u);
}

// ---------------------------------------------------------------------------
// Kernel 1: complex diag state update + C-readout + skip + exact GELU.
// 8 threads per (b,h) pair, float4 loads (fully coalesced: 1KB/wave/array).
// Writes ns_re/ns_im (fp32, d_out) and Y split into hi/lo bf16 (d_ws).
// ---------------------------------------------------------------------------
__global__ __launch_bounds__(256) void s4_update_kernel(
    const float* __restrict__ u,
    const float* __restrict__ sre,  const float* __restrict__ sim,
    const float* __restrict__ dAre, const float* __restrict__ dAim,
    const float* __restrict__ dBre, const float* __restrict__ dBim,
    const float* __restrict__ Cre,  const float* __restrict__ Cim,
    const float* __restrict__ Dv,
    float* __restrict__ nsre, float* __restrict__ nsim,
    short* __restrict__ Yhi, short* __restrict__ Ylo)
{
    const int tid  = threadIdx.x;
    const long gid = (long)blockIdx.x * 256 + tid;
    const int pair = (int)(gid >> 3);         // b*H + h
    const int sub  = tid & 7;                 // 0..7 within pair
    const int n0   = sub << 2;                // 0,4,...,28
    const int h    = pair & (HH - 1);
    const size_t sbase = (size_t)pair * NN + n0;
    const int    pbase = h * NN + n0;

    const f4 a_re = *(const f4*)(dAre + pbase);
    const f4 a_im = *(const f4*)(dAim + pbase);
    const f4 b_re = *(const f4*)(dBre + pbase);
    const f4 b_im = *(const f4*)(dBim + pbase);
    const f4 c_re = *(const f4*)(Cre  + pbase);
    const f4 c_im = *(const f4*)(Cim  + pbase);
    const f4 s_re = *(const f4*)(sre + sbase);
    const f4 s_im = *(const f4*)(sim + sbase);
    const float uv = u[pair];

    f4 nre = a_re * s_re - a_im * s_im + b_re * uv;
    f4 nim = a_re * s_im + a_im * s_re + b_im * uv;

    *(f4*)(nsre + sbase) = nre;
    *(f4*)(nsim + sbase) = nim;

    f4 p = c_re * nre - c_im * nim;
    float part = p[0] + p[1] + p[2] + p[3];
    part += __shfl_xor(part, 1, 64);
    part += __shfl_xor(part, 2, 64);
    part += __shfl_xor(part, 4, 64);

    if (sub == 0) {
        float yv = 2.0f * part + uv * Dv[h];
        float g = 0.5f * yv * (1.0f + erff(yv * 0.70710678118654752f));
        short hi = f2bf(g);
        Yhi[pair] = hi;
        Ylo[pair] = f2bf(g - bf2f(hi));
    }
}

// ---------------------------------------------------------------------------
// Kernel W-split: W fp32 [2H][H] -> Whi/Wlo bf16 (raw short) arrays in d_ws.
// ---------------------------------------------------------------------------
__global__ __launch_bounds__(256) void wsplit_kernel(
    const float* __restrict__ W, short* __restrict__ Whi, short* __restrict__ Wlo)
{
    const size_t i = ((size_t)blockIdx.x * 256 + threadIdx.x) * 4;
    const f4 w = *(const f4*)(W + i);
    s4v hi, lo;
    #pragma unroll
    for (int j = 0; j < 4; ++j) {
        hi[j] = f2bf(w[j]);
        lo[j] = f2bf(w[j] - bf2f(hi[j]));
    }
    *(s4v*)(Whi + i) = hi;
    *(s4v*)(Wlo + i) = lo;
}

// ---------------------------------------------------------------------------
// Kernel 2: z = Y @ W^T + b via 3-term bf16-split MFMA (fp32-grade accuracy),
// fused GLU epilogue. No LDS, no barriers: fragments loaded straight from
// L2-resident bf16 arrays; compiler free to pipeline (no barrier drain).
//
// Block = 256 thr (4 waves), tile 64 rows x 32 paired cols. Wave = 32 rows x
// 16 cols, holding BOTH the z1 frag (fn=0) and matching z2 frag (fn=1) so the
// GLU pairing is lane-local. Grid 32x16 = 512 blocks (2 waves/SIMD).
//
// v_mfma_f32_16x16x32_bf16 layouts (m97/m89-verified):
//   A/B: lane l -> row/col = l&15, k = 8*(l>>4)+j (8 contiguous bf16 = 16B)
//   C/D: lane l, reg r -> col = l&15, row = 4*(l>>4)+r
// ---------------------------------------------------------------------------
__global__ __launch_bounds__(256) void gemm_mfma_glu_kernel(
    const short* __restrict__ Yhi, const short* __restrict__ Ylo,
    const short* __restrict__ Whi, const short* __restrict__ Wlo,
    const float* __restrict__ bias, float* __restrict__ out)
{
    const int tid  = threadIdx.x;
    const int lane = tid & 63;
    const int w    = tid >> 6;
    const int wr   = w >> 1;          // wave row-half of block tile
    const int wc   = w & 1;           // wave col-half
    const int l15  = lane & 15;
    const int g    = lane >> 4;

    const int r0 = blockIdx.y * 64 + wr * 32;   // Y/out row base for wave
    const int jc = blockIdx.x * 32 + wc * 16;   // z-col base (half-relative)

    const size_t rowA0 = (size_t)(r0 + l15) * HH;          // A rows, fr=0
    const size_t rowA1 = rowA0 + (size_t)16 * HH;          // fr=1
    const size_t rowB1 = (size_t)(jc + l15) * HH;          // W rows: z1 cols
    const size_t rowB2 = (size_t)(HH + jc + l15) * HH;     // W rows: z2 cols
    const int koff = g * 8;

    const short* pAh0 = Yhi + rowA0 + koff;
    const short* pAh1 = Yhi + rowA1 + koff;
    const short* pAl0 = Ylo + rowA0 + koff;
    const short* pAl1 = Ylo + rowA1 + koff;
    const short* pBh1 = Whi + rowB1 + koff;
    const short* pBh2 = Whi + rowB2 + koff;
    const short* pBl1 = Wlo + rowB1 + koff;
    const short* pBl2 = Wlo + rowB2 + koff;

    f32x4 acc[2][2] = {};   // [fr][fn]  fn: 0 -> z1, 1 -> z2

    #pragma unroll 2
    for (int k0 = 0; k0 < HH; k0 += 32) {
        const bf16x8 ah0 = *(const bf16x8*)(pAh0 + k0);
        const bf16x8 ah1 = *(const bf16x8*)(pAh1 + k0);
        const bf16x8 al0 = *(const bf16x8*)(pAl0 + k0);
        const bf16x8 al1 = *(const bf16x8*)(pAl1 + k0);
        const bf16x8 bh1 = *(const bf16x8*)(pBh1 + k0);
        const bf16x8 bh2 = *(const bf16x8*)(pBh2 + k0);
        const bf16x8 bl1 = *(const bf16x8*)(pBl1 + k0);
        const bf16x8 bl2 = *(const bf16x8*)(pBl2 + k0);

        acc[0][0] = __builtin_amdgcn_mfma_f32_16x16x32_bf16(ah0, bh1, acc[0][0], 0, 0, 0);
        acc[0][1] = __builtin_amdgcn_mfma_f32_16x16x32_bf16(ah0, bh2, acc[0][1], 0, 0, 0);
        acc[1][0] = __builtin_amdgcn_mfma_f32_16x16x32_bf16(ah1, bh1, acc[1][0], 0, 0, 0);
        acc[1][1] = __builtin_amdgcn_mfma_f32_16x16x32_bf16(ah1, bh2, acc[1][1], 0, 0, 0);

        acc[0][0] = __builtin_amdgcn_mfma_f32_16x16x32_bf16(ah0, bl1, acc[0][0], 0, 0, 0);
        acc[0][1] = __builtin_amdgcn_mfma_f32_16x16x32_bf16(ah0, bl2, acc[0][1], 0, 0, 0);
        acc[1][0] = __builtin_amdgcn_mfma_f32_16x16x32_bf16(ah1, bl1, acc[1][0], 0, 0, 0);
        acc[1][1] = __builtin_amdgcn_mfma_f32_16x16x32_bf16(ah1, bl2, acc[1][1], 0, 0, 0);

        acc[0][0] = __builtin_amdgcn_mfma_f32_16x16x32_bf16(al0, bh1, acc[0][0], 0, 0, 0);
        acc[0][1] = __builtin_amdgcn_mfma_f32_16x16x32_bf16(al0, bh2, acc[0][1], 0, 0, 0);
        acc[1][0] = __builtin_amdgcn_mfma_f32_16x16x32_bf16(al1, bh1, acc[1][0], 0, 0, 0);
        acc[1][1] = __builtin_amdgcn_mfma_f32_16x16x32_bf16(al1, bh2, acc[1][1], 0, 0, 0);
    }

    // epilogue: bias + GLU, pairing lane-local (same l15 col in z1 and z2)
    const float b1 = bias[jc + l15];
    const float b2 = bias[HH + jc + l15];
    #pragma unroll
    for (int fr = 0; fr < 2; ++fr) {
        #pragma unroll
        for (int r = 0; r < 4; ++r) {
            const int row = r0 + 16 * fr + 4 * g + r;
            const float z1 = acc[fr][0][r] + b1;
            const float z2 = acc[fr][1][r] + b2;
            out[(size_t)row * HH + jc + l15] = z1 * (1.0f / (1.0f + expf(-z2)));
        }
    }
}

extern "C" void kernel_launch(void* const* d_in, const int* in_sizes, int n_in,
                              void* d_out, int out_size, void* d_ws, size_t ws_size,
                              hipStream_t stream) {
    const float* u    = (const float*)d_in[0];
    const float* sre  = (const float*)d_in[1];
    const float* sim  = (const float*)d_in[2];
    const float* dAre = (const float*)d_in[3];
    const float* dAim = (const float*)d_in[4];
    const float* dBre = (const float*)d_in[5];
    const float* dBim = (const float*)d_in[6];
    const float* Cre  = (const float*)d_in[7];
    const float* Cim  = (const float*)d_in[8];
    const float* Dv   = (const float*)d_in[9];
    const float* W    = (const float*)d_in[10];
    const float* bias = (const float*)d_in[11];

    float* out   = (float*)d_out;
    float* y_out = out;                                   // [B,H]
    float* nsre  = out + (size_t)BB * HH;                 // [B,H,N]
    float* nsim  = nsre + (size_t)BB * HH * NN;           // [B,H,N]

    // workspace layout (shorts): Yhi[1M] | Ylo[1M] | Whi[2M] | Wlo[2M] = 12MB
    short* Yhi = (short*)d_ws;
    short* Ylo = Yhi + (size_t)BB * HH;
    short* Whi = Ylo + (size_t)BB * HH;
    short* Wlo = Whi + (size_t)2 * HH * HH;

    // W-split: 2M elements / (256*4)
    wsplit_kernel<<<dim3(2 * HH * HH / 1024), 256, 0, stream>>>(W, Whi, Wlo);

    // K1: 8 threads per (b,h) pair
    const long total_threads = (long)BB * HH * 8;
    s4_update_kernel<<<dim3((unsigned)(total_threads / 256)), 256, 0, stream>>>(
        u, sre, sim, dAre, dAim, dBre, dBim, Cre, Cim, Dv, nsre, nsim, Yhi, Ylo);

    // K2: 32 col-tiles x 16 row-tiles = 512 blocks
    gemm_mfma_glu_kernel<<<dim3(32, 16), 256, 0, stream>>>(
        Yhi, Ylo, Whi, Wlo, bias, y_out);
}